// Round 4
// baseline (227.006 us; speedup 1.0000x reference)
//
#include <hip/hip_runtime.h>
#include <hip/hip_bf16.h>

#define N 8192
#define OD 64
#define E_EDGES 262144

#define BM 64
#define KSPLIT 8
#define KS_PER_SPLIT (N / KSPLIT)   // 1024
#define NORM_BLOCKS 2048
#define NPARTS 8                    // atomic-target partitions (~per-XCD)

typedef __attribute__((ext_vector_type(8))) short bf16x8;
typedef __attribute__((ext_vector_type(4))) float f32x4;

__device__ __forceinline__ unsigned short f2bf(float f) {
    union { float f; unsigned u; } v; v.f = f;
    unsigned r = (v.u + 0x7fffu + ((v.u >> 16) & 1u)) >> 16;  // RNE
    return (unsigned short)r;
}

// ---------------- sum of squares of attn -> per-block partials ----------------
__global__ __launch_bounds__(256) void norm_sq_kernel(const float* __restrict__ attn,
                                                      float* __restrict__ part) {
    const float4* a4 = (const float4*)attn;
    const int total = (N * (long)N) / 4;
    float s = 0.f;
    for (long i = (long)blockIdx.x * blockDim.x + threadIdx.x; i < total;
         i += (long)NORM_BLOCKS * blockDim.x) {
        float4 v = a4[i];
        s += v.x * v.x + v.y * v.y + v.z * v.z + v.w * v.w;
    }
    for (int off = 32; off > 0; off >>= 1) s += __shfl_down(s, off, 64);
    __shared__ float wpart[4];
    int wid = threadIdx.x >> 6;
    if ((threadIdx.x & 63) == 0) wpart[wid] = s;
    __syncthreads();
    if (threadIdx.x == 0) part[blockIdx.x] = wpart[0] + wpart[1] + wpart[2] + wpart[3];
}

// ---------------- convert W [N][OD] f32 -> wt [OD][N] bf16 (LDS transpose)
//                  + zero the out_part atomic targets ----------------
__global__ __launch_bounds__(256) void convert_w_kernel(const float* __restrict__ w,
                                                        unsigned short* __restrict__ wt,
                                                        float4* __restrict__ out_part4) {
    // zero out_part: 8 * N*OD floats = 1,048,576 float4 over 2048 blocks x 256 thr x 2
    int zi = blockIdx.x * 256 + threadIdx.x;
    out_part4[zi] = float4{0.f, 0.f, 0.f, 0.f};
    out_part4[zi + 524288] = float4{0.f, 0.f, 0.f, 0.f};

    if (blockIdx.x < 128) {  // transpose-convert: block b owns k-range [b*64, b*64+64)
        __shared__ unsigned short lds[64][80];  // stride 80 ushorts = 160 B (16B-aligned rows)
        const int kb = blockIdx.x * 64;
        const int t = threadIdx.x;
        #pragma unroll
        for (int p = 0; p < 4; ++p) {
            int idx = p * 1024 + t * 4;
            int r = idx >> 6, c = idx & 63;     // r = local k, c = col
            float4 v = *(const float4*)(&w[(size_t)(kb + r) * OD + c]);
            lds[c + 0][r] = f2bf(v.x);
            lds[c + 1][r] = f2bf(v.y);
            lds[c + 2][r] = f2bf(v.z);
            lds[c + 3][r] = f2bf(v.w);
        }
        __syncthreads();
        const int col = t >> 2, j0 = (t & 3) * 16;
        #pragma unroll
        for (int u = 0; u < 2; ++u) {
            *(bf16x8*)(wt + (size_t)col * N + kb + j0 + u * 8) =
                *(const bf16x8*)(&lds[col][j0 + u * 8]);
        }
    }
}

// ---------------- y_part[split] = x[:, ksplit] @ W[ksplit, :] — register-only MFMA ----------------
__global__ __launch_bounds__(256) void gemm_kernel(const float* __restrict__ x,
                                                   const unsigned short* __restrict__ wt,
                                                   float* __restrict__ y_part) {
    const int tid = threadIdx.x;
    const int wv = tid >> 6;
    const int lane = tid & 63;
    const int lrow = lane & 15;   // A-row / B-col within 16x16 fragment
    const int g = lane >> 4;      // k-group (8 elems each)
    const int row = blockIdx.x * BM + wv * 16 + lrow;
    const int split = blockIdx.y;
    const int k0 = split * KS_PER_SPLIT;

    f32x4 acc[4] = {f32x4{0,0,0,0}, f32x4{0,0,0,0}, f32x4{0,0,0,0}, f32x4{0,0,0,0}};

    const float* xp = x + (size_t)row * N + k0 + g * 8;
    const unsigned short* wp = wt + k0 + g * 8;

    #pragma unroll 4
    for (int ks = 0; ks < KS_PER_SPLIT / 32; ++ks) {   // 32 iters
        float4 v0 = *(const float4*)(xp + ks * 32);
        float4 v1 = *(const float4*)(xp + ks * 32 + 4);
        bf16x8 a;
        a[0] = f2bf(v0.x); a[1] = f2bf(v0.y); a[2] = f2bf(v0.z); a[3] = f2bf(v0.w);
        a[4] = f2bf(v1.x); a[5] = f2bf(v1.y); a[6] = f2bf(v1.z); a[7] = f2bf(v1.w);
        #pragma unroll
        for (int cf = 0; cf < 4; ++cf) {
            bf16x8 b = *(const bf16x8*)(wp + (size_t)(cf * 16 + lrow) * N + ks * 32);
            acc[cf] = __builtin_amdgcn_mfma_f32_16x16x32_bf16(a, b, acc[cf], 0, 0, 0);
        }
    }
    // C/D layout: col = lane&15, row = (lane>>4)*4 + i (verified)
    float* yp = y_part + (size_t)split * N * OD + ((size_t)blockIdx.x * BM + wv * 16 + g * 4) * OD;
    #pragma unroll
    for (int cf = 0; cf < 4; ++cf) {
        #pragma unroll
        for (int i = 0; i < 4; ++i) {
            yp[i * OD + cf * 16 + lrow] = acc[cf][i];
        }
    }
}

// ---------------- y = sum over splits of y_part ----------------
__global__ __launch_bounds__(256) void reduce_y_kernel(const float4* __restrict__ y_part,
                                                       float4* __restrict__ y) {
    int i = blockIdx.x * 256 + threadIdx.x;   // 0 .. 131071 (N*OD/4)
    const int stride = N * OD / 4;
    float4 s = y_part[i];
    #pragma unroll
    for (int p = 1; p < KSPLIT; ++p) {
        float4 v = y_part[p * stride + i];
        s.x += v.x; s.y += v.y; s.z += v.z; s.w += v.w;
    }
    y[i] = s;
}

// ---------------- edge scatter into 8-way partitioned targets ----------------
__global__ __launch_bounds__(256) void scatter_kernel(const float* __restrict__ values,
                                                      const float* __restrict__ attn,
                                                      const int* __restrict__ row,
                                                      const int* __restrict__ col,
                                                      const float* __restrict__ y,
                                                      float* __restrict__ out_part) {
    const int e = blockIdx.x * 4 + (threadIdx.x >> 6);
    const int lane = threadIdx.x & 63;
    const int part = blockIdx.x & (NPARTS - 1);   // blockIdx round-robins XCDs -> ~L2-local atomics
    const int r = row[e];
    const int c = col[e];
    const float ev = values[e] * attn[(size_t)r * N + c];
    atomicAdd(&out_part[(size_t)part * (N * OD) + r * OD + lane], ev * y[c * OD + lane]);
}

// ---------------- out = sum of partitions; block 0 also finalizes norm ----------------
__global__ __launch_bounds__(256) void reduce_out_kernel(const float4* __restrict__ out_part4,
                                                         float4* __restrict__ out4,
                                                         const float* __restrict__ norm_part,
                                                         float* __restrict__ out_norm) {
    int i = blockIdx.x * 256 + threadIdx.x;   // 0 .. 131071
    const int stride = N * OD / 4;
    float4 s = out_part4[i];
    #pragma unroll
    for (int p = 1; p < NPARTS; ++p) {
        float4 v = out_part4[p * stride + i];
        s.x += v.x; s.y += v.y; s.z += v.z; s.w += v.w;
    }
    out4[i] = s;

    if (blockIdx.x == 0) {
        float t = 0.f;
        #pragma unroll
        for (int k = 0; k < NORM_BLOCKS / 256; ++k) t += norm_part[k * 256 + threadIdx.x];
        for (int off = 32; off > 0; off >>= 1) t += __shfl_down(t, off, 64);
        __shared__ float wpart[4];
        int wid = threadIdx.x >> 6;
        if ((threadIdx.x & 63) == 0) wpart[wid] = t;
        __syncthreads();
        if (threadIdx.x == 0) *out_norm = sqrtf(wpart[0] + wpart[1] + wpart[2] + wpart[3]);
    }
}

extern "C" void kernel_launch(void* const* d_in, const int* in_sizes, int n_in,
                              void* d_out, int out_size, void* d_ws, size_t ws_size,
                              hipStream_t stream) {
    const float* x      = (const float*)d_in[0];
    const float* attn   = (const float*)d_in[1];
    const float* weight = (const float*)d_in[2];
    const float* values = (const float*)d_in[3];
    const int*   row    = (const int*)d_in[4];
    const int*   col    = (const int*)d_in[5];
    float* out = (float*)d_out;

    char* wsb = (char*)d_ws;
    float*          norm_part = (float*)wsb;                          // 8 KB
    unsigned short* wt        = (unsigned short*)(wsb + (1u << 20));  // 1 MB
    float*          y         = (float*)(wsb + (2u << 20));           // 2 MB
    float*          y_part    = (float*)(wsb + (4u << 20));           // 16 MB
    float*          out_part  = (float*)(wsb + (20u << 20));          // 16 MB (8 partitions)

    convert_w_kernel<<<2048, 256, 0, stream>>>(weight, wt, (float4*)out_part);
    gemm_kernel<<<dim3(N / BM, KSPLIT), 256, 0, stream>>>(x, wt, y_part);
    reduce_y_kernel<<<N * OD / 4 / 256, 256, 0, stream>>>((const float4*)y_part, (float4*)y);
    norm_sq_kernel<<<NORM_BLOCKS, 256, 0, stream>>>(attn, norm_part);
    scatter_kernel<<<E_EDGES / 4, 256, 0, stream>>>(values, attn, row, col, y, out_part);
    reduce_out_kernel<<<N * OD / 4 / 256, 256, 0, stream>>>((const float4*)out_part, (float4*)out,
                                                            norm_part, out + (size_t)N * OD);
}

// Round 5
// 205.671 us; speedup vs baseline: 1.1037x; 1.1037x over previous
//
#include <hip/hip_runtime.h>
#include <hip/hip_bf16.h>

#define N 8192
#define OD 64
#define E_EDGES 262144

#define BM 64
#define KSPLIT 8
#define KS_PER_SPLIT (N / KSPLIT)   // 1024
#define NORM_BLOCKS 2048
#define SCAT_BLOCKS 8192

typedef __attribute__((ext_vector_type(8))) short bf16x8;
typedef __attribute__((ext_vector_type(4))) float f32x4;

__device__ __forceinline__ unsigned short f2bf(float f) {
    union { float f; unsigned u; } v; v.f = f;
    unsigned r = (v.u + 0x7fffu + ((v.u >> 16) & 1u)) >> 16;  // RNE
    return (unsigned short)r;
}

// ---- K1: norm partials + W transpose-convert + zero y/out (fused; one big stream) ----
__global__ __launch_bounds__(256) void prep_kernel(const float* __restrict__ attn,
                                                   const float* __restrict__ w,
                                                   unsigned short* __restrict__ wt,
                                                   float4* __restrict__ y4,
                                                   float4* __restrict__ out4,
                                                   float* __restrict__ part) {
    const int bid = blockIdx.x, t = threadIdx.x;

    // zero y (131072 f4) + out (131072 f4): 2048 blocks x 128 f4
    if (t < 128) {
        int zi = bid * 128 + t;
        float4 z{0.f, 0.f, 0.f, 0.f};
        if (zi < 131072) y4[zi] = z;
        else out4[zi - 131072] = z;
    }

    // W [N][OD] f32 -> wt [OD][N] bf16, LDS transpose; blocks 0..127, k-range [bid*64, +64)
    if (bid < 128) {
        __shared__ unsigned short lds[64][80];  // +pad rows, 16B-aligned
        const int kb = bid * 64;
        #pragma unroll
        for (int p = 0; p < 4; ++p) {
            int idx = p * 1024 + t * 4;
            int r = idx >> 6, c = idx & 63;     // r = local k, c = col
            float4 v = *(const float4*)(&w[(size_t)(kb + r) * OD + c]);
            lds[c + 0][r] = f2bf(v.x);
            lds[c + 1][r] = f2bf(v.y);
            lds[c + 2][r] = f2bf(v.z);
            lds[c + 3][r] = f2bf(v.w);
        }
        __syncthreads();
        const int colx = t >> 2, j0 = (t & 3) * 16;
        #pragma unroll
        for (int u = 0; u < 2; ++u) {
            *(bf16x8*)(wt + (size_t)colx * N + kb + j0 + u * 8) =
                *(const bf16x8*)(&lds[colx][j0 + u * 8]);
        }
    }

    // norm-sq partial over attn (grid-stride, all 2048 blocks)
    const float4* a4 = (const float4*)attn;
    const int total = (N * (long)N) / 4;
    float s = 0.f;
    for (long i = (long)bid * 256 + t; i < total; i += (long)NORM_BLOCKS * 256) {
        float4 v = a4[i];
        s += v.x * v.x + v.y * v.y + v.z * v.z + v.w * v.w;
    }
    for (int off = 32; off > 0; off >>= 1) s += __shfl_down(s, off, 64);
    __shared__ float wpart[4];
    int wid = t >> 6;
    if ((t & 63) == 0) wpart[wid] = s;
    __syncthreads();
    if (t == 0) part[bid] = wpart[0] + wpart[1] + wpart[2] + wpart[3];
}

// ---- K2: y += x[:,split] @ W[split,:] — register-only MFMA, atomic split-K epilogue ----
__global__ __launch_bounds__(256) void gemm_kernel(const float* __restrict__ x,
                                                   const unsigned short* __restrict__ wt,
                                                   float* __restrict__ y) {
    const int tid = threadIdx.x;
    const int wv = tid >> 6;
    const int lane = tid & 63;
    const int lrow = lane & 15;   // A-row / B-col within 16x16 fragment
    const int g = lane >> 4;      // k-group (8 elems each)
    const int row = blockIdx.x * BM + wv * 16 + lrow;
    const int k0 = blockIdx.y * KS_PER_SPLIT;

    f32x4 acc[4] = {f32x4{0,0,0,0}, f32x4{0,0,0,0}, f32x4{0,0,0,0}, f32x4{0,0,0,0}};

    const float* xp = x + (size_t)row * N + k0 + g * 8;
    const unsigned short* wp = wt + k0 + g * 8;

    #pragma unroll 4
    for (int ks = 0; ks < KS_PER_SPLIT / 32; ++ks) {   // 32 iters
        float4 v0 = *(const float4*)(xp + ks * 32);
        float4 v1 = *(const float4*)(xp + ks * 32 + 4);
        bf16x8 a;
        a[0] = f2bf(v0.x); a[1] = f2bf(v0.y); a[2] = f2bf(v0.z); a[3] = f2bf(v0.w);
        a[4] = f2bf(v1.x); a[5] = f2bf(v1.y); a[6] = f2bf(v1.z); a[7] = f2bf(v1.w);
        #pragma unroll
        for (int cf = 0; cf < 4; ++cf) {
            bf16x8 b = *(const bf16x8*)(wp + (size_t)(cf * 16 + lrow) * N + ks * 32);
            acc[cf] = __builtin_amdgcn_mfma_f32_16x16x32_bf16(a, b, acc[cf], 0, 0, 0);
        }
    }
    // C/D layout: col = lane&15, row = (lane>>4)*4 + i (verified); split-K accumulate via atomics
    float* yp = y + ((size_t)blockIdx.x * BM + wv * 16 + g * 4) * OD;
    #pragma unroll
    for (int cf = 0; cf < 4; ++cf) {
        #pragma unroll
        for (int i = 0; i < 4; ++i) {
            atomicAdd(&yp[i * OD + cf * 16 + lrow], acc[cf][i]);
        }
    }
}

// ---- K3: edge scatter (grid-strided) + norm finalize in one extra block ----
__global__ __launch_bounds__(256) void scatter_kernel(const float* __restrict__ values,
                                                      const float* __restrict__ attn,
                                                      const int* __restrict__ row,
                                                      const int* __restrict__ col,
                                                      const float* __restrict__ y,
                                                      float* __restrict__ out,
                                                      const float* __restrict__ part,
                                                      float* __restrict__ out_norm) {
    if (blockIdx.x == SCAT_BLOCKS) {   // norm finalize
        float s = 0.f;
        #pragma unroll
        for (int k = 0; k < NORM_BLOCKS / 256; ++k) s += part[k * 256 + threadIdx.x];
        for (int off = 32; off > 0; off >>= 1) s += __shfl_down(s, off, 64);
        __shared__ float wp[4];
        int wid = threadIdx.x >> 6;
        if ((threadIdx.x & 63) == 0) wp[wid] = s;
        __syncthreads();
        if (threadIdx.x == 0) *out_norm = sqrtf(wp[0] + wp[1] + wp[2] + wp[3]);
        return;
    }
    const int lane = threadIdx.x & 63;
    int e = blockIdx.x * 4 + (threadIdx.x >> 6);
    #pragma unroll
    for (int it = 0; it < E_EDGES / (SCAT_BLOCKS * 4); ++it, e += SCAT_BLOCKS * 4) {
        const int r = row[e];
        const int c = col[e];
        const float ev = values[e] * attn[(size_t)r * N + c];
        atomicAdd(&out[r * OD + lane], ev * y[c * OD + lane]);
    }
}

extern "C" void kernel_launch(void* const* d_in, const int* in_sizes, int n_in,
                              void* d_out, int out_size, void* d_ws, size_t ws_size,
                              hipStream_t stream) {
    const float* x      = (const float*)d_in[0];
    const float* attn   = (const float*)d_in[1];
    const float* weight = (const float*)d_in[2];
    const float* values = (const float*)d_in[3];
    const int*   row    = (const int*)d_in[4];
    const int*   col    = (const int*)d_in[5];
    float* out = (float*)d_out;

    char* wsb = (char*)d_ws;
    float*          norm_part = (float*)wsb;                          // 8 KB
    unsigned short* wt        = (unsigned short*)(wsb + (1u << 20));  // 1 MB
    float*          y         = (float*)(wsb + (2u << 20));           // 2 MB

    prep_kernel<<<NORM_BLOCKS, 256, 0, stream>>>(attn, weight, wt, (float4*)y,
                                                 (float4*)out, norm_part);
    gemm_kernel<<<dim3(N / BM, KSPLIT), 256, 0, stream>>>(x, wt, y);
    scatter_kernel<<<SCAT_BLOCKS + 1, 256, 0, stream>>>(values, attn, row, col, y, out,
                                                        norm_part, out + (size_t)N * OD);
}